// Round 13
// baseline (126.401 us; speedup 1.0000x reference)
//
#include <hip/hip_runtime.h>
#include <hip/hip_cooperative_groups.h>

namespace cg = cooperative_groups;

// Problem constants (fixed by setup_inputs): B=4, T=28, N=1024, D=3
constexpr int Bc = 4;
constexpr int Tc = 28;
constexpr int Nc = 1024;
constexpr int Dc = 3;
constexpr int BT = Bc * Tc;       // 112
constexpr int TQ = 256;           // targets per chunk
constexpr int NQ = Nc / TQ;       // 4 chunks (R10 topology: empirical best)

__device__ __forceinline__ float sl1(float d) {
    d = fabsf(d);
    return d < 1.0f ? 0.5f * d * d : d - 0.5f;
}

// key = v with low 10 mantissa bits replaced by the GLOBAL target index.
// fmin over keys == argmin over v truncated to 2^-13 relative; ties -> lowest
// idx for positive keys (jnp first-occurrence); R10/R11 measured absmax 0.0.
__device__ __forceinline__ float pack_key(float v, unsigned m) {
    return __uint_as_float((__float_as_uint(v) & 0xFFFFFC00u) | m);
}

// ---------------------------------------------------------------------------
// Cooperative fused kernel: 448 blocks = 112 bt x 4 chunks, 256 thr, 4 preds/thr.
// Phase 1 == R10's chamfer (packed-key fmin argmin, LDS-staged chunk, PF=4
// register double-buffer, PLAIN float4 key stores — R12 post-mortem: atomic
// publish serializes across non-coherent XCD L2s, never again).
// grid.sync() replaces the second kernel dispatch; phase 2 runs in the 112
// th==0 blocks whose preds are still live in registers from phase 1.
// Block 0 zeroes out[] before the barrier -> zero memset nodes, ONE graph node.
// ---------------------------------------------------------------------------
__global__ __launch_bounds__(256) void chamfer_coop_kernel(
    const float* __restrict__ X, const float* __restrict__ Tg,
    const float* __restrict__ W,
    float4* __restrict__ bestkP, float* __restrict__ out)
{
    __shared__ float4 sT4[TQ];      // 4 KB packed chunk [x,y,z,||t||^2]
    __shared__ float sred[4][8];

    const int bt  = blockIdx.x >> 2;
    const int th  = blockIdx.x & 3;
    const int tid = threadIdx.x;

    if (blockIdx.x == 0 && tid < 2) out[tid] = 0.0f;   // ordered by grid.sync

    // ---- preds 4tid..4tid+3 via three coalesced float4 loads ----
    const float4* x4 = (const float4*)(X + (size_t)bt * (Nc * Dc));
    const float4 a0 = x4[3 * tid + 0];
    const float4 a1 = x4[3 * tid + 1];
    const float4 a2 = x4[3 * tid + 2];
    const float cx[4] = {-2.f * a0.x, -2.f * a0.w, -2.f * a1.z, -2.f * a2.y};
    const float cy[4] = {-2.f * a0.y, -2.f * a1.x, -2.f * a1.w, -2.f * a2.z};
    const float cz[4] = {-2.f * a0.z, -2.f * a1.y, -2.f * a2.x, -2.f * a2.w};

    // ---- wave 0 stages + packs the 256-target chunk (4 targets/lane) ----
    if (tid < 64) {
        const float4* tg4 = (const float4*)(Tg + (size_t)bt * (Nc * Dc) + th * (TQ * 3));
        const float4 r0 = tg4[3 * tid + 0];
        const float4 r1 = tg4[3 * tid + 1];
        const float4 r2 = tg4[3 * tid + 2];
        sT4[4 * tid + 0] = make_float4(r0.x, r0.y, r0.z, fmaf(r0.x, r0.x, fmaf(r0.y, r0.y, r0.z * r0.z)));
        sT4[4 * tid + 1] = make_float4(r0.w, r1.x, r1.y, fmaf(r0.w, r0.w, fmaf(r1.x, r1.x, r1.y * r1.y)));
        sT4[4 * tid + 2] = make_float4(r1.z, r1.w, r2.x, fmaf(r1.z, r1.z, fmaf(r1.w, r1.w, r2.x * r2.x)));
        sT4[4 * tid + 3] = make_float4(r2.y, r2.z, r2.w, fmaf(r2.y, r2.y, fmaf(r2.z, r2.z, r2.w * r2.w)));
    }
    __syncthreads();

    const unsigned mgBase = (unsigned)(th * TQ);   // global index of chunk start
    float best[4] = {3.4e38f, 3.4e38f, 3.4e38f, 3.4e38f};

    constexpr int PF = 4;           // register double-buffer depth
    float4 bufA[PF], bufB[PF];
    #pragma unroll
    for (int j = 0; j < PF; ++j) bufA[j] = sT4[j];

    for (int m0 = 0; m0 < TQ; m0 += 2 * PF) {
        #pragma unroll
        for (int j = 0; j < PF; ++j) bufB[j] = sT4[m0 + PF + j];
        #pragma unroll
        for (int j = 0; j < PF; j += 2) {
            const float4 t0 = bufA[j], t1 = bufA[j + 1];
            const unsigned mg0 = mgBase + m0 + j, mg1 = mg0 + 1;
            #pragma unroll
            for (int k = 0; k < 4; ++k) {
                float v0 = fmaf(cx[k], t0.x, fmaf(cy[k], t0.y, fmaf(cz[k], t0.z, t0.w)));
                float v1 = fmaf(cx[k], t1.x, fmaf(cy[k], t1.y, fmaf(cz[k], t1.z, t1.w)));
                best[k] = fminf(fminf(pack_key(v0, mg0), pack_key(v1, mg1)), best[k]);
            }
        }
        #pragma unroll
        for (int j = 0; j < PF; ++j) bufA[j] = sT4[(m0 + 2 * PF + j) & (TQ - 1)];
        #pragma unroll
        for (int j = 0; j < PF; j += 2) {
            const float4 t0 = bufB[j], t1 = bufB[j + 1];
            const unsigned mg0 = mgBase + m0 + PF + j, mg1 = mg0 + 1;
            #pragma unroll
            for (int k = 0; k < 4; ++k) {
                float v0 = fmaf(cx[k], t0.x, fmaf(cy[k], t0.y, fmaf(cz[k], t0.z, t0.w)));
                float v1 = fmaf(cx[k], t1.x, fmaf(cy[k], t1.y, fmaf(cz[k], t1.z, t1.w)));
                best[k] = fminf(fminf(pack_key(v0, mg0), pack_key(v1, mg1)), best[k]);
            }
        }
    }

    // plain coalesced float4 key store (NO atomics)
    bestkP[((size_t)th * BT + bt) * 256 + tid] = make_float4(best[0], best[1], best[2], best[3]);

    // ================= grid-wide barrier replaces the K2 dispatch =================
    cg::this_grid().sync();
    if (th != 0) return;

    // =========== phase 2 (old K2 body) in the 112 th==0 blocks ===========
    const size_t rb = (size_t)bt * 256 + tid;
    float4 bk = bestkP[rb];
    #pragma unroll
    for (int q = 1; q < NQ; ++q) {
        const float4 k2 = bestkP[(size_t)q * BT * 256 + rb];
        bk.x = fminf(bk.x, k2.x);
        bk.y = fminf(bk.y, k2.y);
        bk.z = fminf(bk.z, k2.z);
        bk.w = fminf(bk.w, k2.w);
    }
    const int idx[4] = {
        (int)(__float_as_uint(bk.x) & 1023u),
        (int)(__float_as_uint(bk.y) & 1023u),
        (int)(__float_as_uint(bk.z) & 1023u),
        (int)(__float_as_uint(bk.w) & 1023u)
    };

    // preds still live in registers from phase 1
    const float px[4] = {a0.x, a0.w, a1.z, a2.y};
    const float py[4] = {a0.y, a1.x, a1.w, a2.z};
    const float pz[4] = {a0.z, a1.y, a2.x, a2.w};

    // gather winners, smooth-L1
    const float* tb = Tg + (size_t)bt * (Nc * Dc);
    float s = 0.0f;
    #pragma unroll
    for (int k = 0; k < 4; ++k) {
        const float tx = tb[idx[k] * 3 + 0];
        const float ty = tb[idx[k] * 3 + 1];
        const float tz = tb[idx[k] * 3 + 2];
        s += sl1(px[k] - tx) + sl1(py[k] - ty) + sl1(pz[k] - tz);
    }

    // coalesced target re-read for centroid sums (12 KB, L2-warm)
    const float4* t4 = (const float4*)tb;
    const float4 r0 = t4[3 * tid + 0];
    const float4 r1 = t4[3 * tid + 1];
    const float4 r2 = t4[3 * tid + 2];

    float vals[7] = {
        s,
        px[0] + px[1] + px[2] + px[3],
        py[0] + py[1] + py[2] + py[3],
        pz[0] + pz[1] + pz[2] + pz[3],
        r0.x + r0.w + r1.z + r2.y,
        r0.y + r1.x + r1.w + r2.z,
        r0.z + r1.y + r2.x + r2.w
    };
    const int lane = tid & 63, wid = tid >> 6;
    #pragma unroll
    for (int k = 0; k < 7; ++k) {
        float v = vals[k];
        #pragma unroll
        for (int off = 32; off; off >>= 1) v += __shfl_down(v, off, 64);
        if (lane == 0) sred[wid][k] = v;
    }
    __syncthreads();
    if (tid == 0) {
        float tot[7];
        #pragma unroll
        for (int k = 0; k < 7; ++k)
            tot[k] = sred[0][k] + sred[1][k] + sred[2][k] + sred[3][k];
        // loss contribution: w_bt * (sl1 sum / (N*D)) / B
        atomicAdd(out, tot[0] * W[bt] * (1.0f / (Nc * Dc)) * (1.0f / Bc));
        // centroid contribution for this bt
        const float inv = 1.0f / Nc;
        float lc = sl1((tot[1] - tot[4]) * inv)
                 + sl1((tot[2] - tot[5]) * inv)
                 + sl1((tot[3] - tot[6]) * inv);
        atomicAdd(out + 1, lc * (1.0f / (Bc * Dc)));   // lossc = sum / (B*3)
    }
}

extern "C" void kernel_launch(void* const* d_in, const int* in_sizes, int n_in,
                              void* d_out, int out_size, void* d_ws, size_t ws_size,
                              hipStream_t stream) {
    const float* X  = (const float*)d_in[0];  // X_v        [4,28,1024,3]
    const float* Tg = (const float*)d_in[1];  // target_X_v [4,28,1024,3]
    const float* W  = (const float*)d_in[2];  // weights    [4,28]
    float* out = (float*)d_out;               // {loss, lossc}
    float4* bestkP = (float4*)d_ws;           // [NQ*BT*256] packed key groups

    void* args[] = {(void*)&X, (void*)&Tg, (void*)&W, (void*)&bestkP, (void*)&out};
    hipLaunchCooperativeKernel((void*)chamfer_coop_kernel,
                               dim3(BT * NQ), dim3(256), args, 0, stream);
}

// Round 14
// 80.123 us; speedup vs baseline: 1.5776x; 1.5776x over previous
//
#include <hip/hip_runtime.h>

// Problem constants (fixed by setup_inputs): B=4, T=28, N=1024, D=3
constexpr int Bc = 4;
constexpr int Tc = 28;
constexpr int Nc = 1024;
constexpr int Dc = 3;
constexpr int BT = Bc * Tc;       // 112
constexpr int TQ = 256;           // targets per chunk
constexpr int NQ = Nc / TQ;       // 4 chunks (R7/R10 topology: empirical best)

// ws layout: bestkP [NQ][BT][256] float4 — packed argmin keys, idx in low 10
// mantissa bits. All slots written before read -> no ws memsets.
// R12/R13 post-mortem: cross-block combine MUST be plain stores + separate
// consumer kernel. atomicMin-publish (+42us) and coop grid.sync (+46us) both
// lose badly to the 2-node chain on 8 non-coherent XCDs.

__device__ __forceinline__ float sl1(float d) {
    d = fabsf(d);
    return d < 1.0f ? 0.5f * d * d : d - 0.5f;
}

// key = v with low 10 mantissa bits replaced by the GLOBAL target index.
// fmin over keys == argmin over v truncated to 2^-13 relative, ties -> lowest
// idx (positive keys) == jnp.argmin first-occurrence; measured absmax 0.0
// (R10/R11): truncation-induced flips never materialized above threshold.
__device__ __forceinline__ float pack_key(float v, unsigned m) {
    return __uint_as_float((__float_as_uint(v) & 0xFFFFFC00u) | m);
}

// ---------------------------------------------------------------------------
// K1: 448 blocks = 112 bt x 4 target-chunks, 256 thr, 4 preds/thread.
// Best measured structure (R10, 80.2us total): LDS-staged packed chunk
// [x,y,z,||t||^2], broadcast ds_read_b128, PF=4 register double-buffer,
// per 2 targets per pred: 6 fma + 2 v_and_or_b32 + 1 v_min3_f32.
// Block 0 zeroes out[] (graph edge orders it before K2's atomics).
// ---------------------------------------------------------------------------
__global__ __launch_bounds__(256) void chamfer_kernel(
    const float* __restrict__ X, const float* __restrict__ Tg,
    float4* __restrict__ bestkP, float* __restrict__ out)
{
    __shared__ float4 sT4[TQ];      // 4 KB packed chunk

    const int bt  = blockIdx.x >> 2;
    const int th  = blockIdx.x & 3;
    const int tid = threadIdx.x;

    if (blockIdx.x == 0 && tid < 2) out[tid] = 0.0f;   // d_out is 0xAA-poisoned

    // ---- preds 4tid..4tid+3 via three coalesced float4 loads ----
    const float4* x4 = (const float4*)(X + (size_t)bt * (Nc * Dc));
    const float4 a0 = x4[3 * tid + 0];
    const float4 a1 = x4[3 * tid + 1];
    const float4 a2 = x4[3 * tid + 2];
    const float cx[4] = {-2.f * a0.x, -2.f * a0.w, -2.f * a1.z, -2.f * a2.y};
    const float cy[4] = {-2.f * a0.y, -2.f * a1.x, -2.f * a1.w, -2.f * a2.z};
    const float cz[4] = {-2.f * a0.z, -2.f * a1.y, -2.f * a2.x, -2.f * a2.w};

    // ---- wave 0 stages + packs the 256-target chunk (4 targets/lane) ----
    if (tid < 64) {
        const float4* tg4 = (const float4*)(Tg + (size_t)bt * (Nc * Dc) + th * (TQ * 3));
        const float4 r0 = tg4[3 * tid + 0];
        const float4 r1 = tg4[3 * tid + 1];
        const float4 r2 = tg4[3 * tid + 2];
        sT4[4 * tid + 0] = make_float4(r0.x, r0.y, r0.z, fmaf(r0.x, r0.x, fmaf(r0.y, r0.y, r0.z * r0.z)));
        sT4[4 * tid + 1] = make_float4(r0.w, r1.x, r1.y, fmaf(r0.w, r0.w, fmaf(r1.x, r1.x, r1.y * r1.y)));
        sT4[4 * tid + 2] = make_float4(r1.z, r1.w, r2.x, fmaf(r1.z, r1.z, fmaf(r1.w, r1.w, r2.x * r2.x)));
        sT4[4 * tid + 3] = make_float4(r2.y, r2.z, r2.w, fmaf(r2.y, r2.y, fmaf(r2.z, r2.z, r2.w * r2.w)));
    }
    __syncthreads();

    const unsigned mgBase = (unsigned)(th * TQ);   // global index of chunk start
    float best[4] = {3.4e38f, 3.4e38f, 3.4e38f, 3.4e38f};

    constexpr int PF = 4;           // register double-buffer depth
    float4 bufA[PF], bufB[PF];
    #pragma unroll
    for (int j = 0; j < PF; ++j) bufA[j] = sT4[j];

    for (int m0 = 0; m0 < TQ; m0 += 2 * PF) {
        #pragma unroll
        for (int j = 0; j < PF; ++j) bufB[j] = sT4[m0 + PF + j];
        #pragma unroll
        for (int j = 0; j < PF; j += 2) {
            const float4 t0 = bufA[j], t1 = bufA[j + 1];
            const unsigned mg0 = mgBase + m0 + j, mg1 = mg0 + 1;
            #pragma unroll
            for (int k = 0; k < 4; ++k) {
                float v0 = fmaf(cx[k], t0.x, fmaf(cy[k], t0.y, fmaf(cz[k], t0.z, t0.w)));
                float v1 = fmaf(cx[k], t1.x, fmaf(cy[k], t1.y, fmaf(cz[k], t1.z, t1.w)));
                best[k] = fminf(fminf(pack_key(v0, mg0), pack_key(v1, mg1)), best[k]);
            }
        }
        #pragma unroll
        for (int j = 0; j < PF; ++j) bufA[j] = sT4[(m0 + 2 * PF + j) & (TQ - 1)];
        #pragma unroll
        for (int j = 0; j < PF; j += 2) {
            const float4 t0 = bufB[j], t1 = bufB[j + 1];
            const unsigned mg0 = mgBase + m0 + PF + j, mg1 = mg0 + 1;
            #pragma unroll
            for (int k = 0; k < 4; ++k) {
                float v0 = fmaf(cx[k], t0.x, fmaf(cy[k], t0.y, fmaf(cz[k], t0.z, t0.w)));
                float v1 = fmaf(cx[k], t1.x, fmaf(cy[k], t1.y, fmaf(cz[k], t1.z, t1.w)));
                best[k] = fminf(fminf(pack_key(v0, mg0), pack_key(v1, mg1)), best[k]);
            }
        }
    }

    // one coalesced float4 store: keys carry both value and global index
    bestkP[((size_t)th * BT + bt) * 256 + tid] = make_float4(best[0], best[1], best[2], best[3]);
}

// ---------------------------------------------------------------------------
// K2: 112 blocks (one per bt), 256 thr, 4 preds/thread. Componentwise fmin
// over the 4 chunk keys (ties -> lowest global idx), extract idx from low 10
// bits, gather winning targets, smooth-L1, block-reduce, atomicAdd -> out[0].
// Each block also computes its bt's centroid loss term (coalesced re-read of
// X and Tg, L2-warm) -> out[1]. out was zeroed by K1 block 0.
// ---------------------------------------------------------------------------
__global__ __launch_bounds__(256) void gather_finalize_kernel(
    const float* __restrict__ X, const float* __restrict__ Tg,
    const float* __restrict__ W,
    const float4* __restrict__ bestkP, float* __restrict__ out)
{
    __shared__ float sred[4][8];
    const int bt  = blockIdx.x;
    const int tid = threadIdx.x;
    const size_t rb = (size_t)bt * 256 + tid;

    // ---- combine the 4 chunk keys ----
    float4 bk = bestkP[rb];
    #pragma unroll
    for (int q = 1; q < NQ; ++q) {
        const float4 k2 = bestkP[(size_t)q * BT * 256 + rb];
        bk.x = fminf(bk.x, k2.x);
        bk.y = fminf(bk.y, k2.y);
        bk.z = fminf(bk.z, k2.z);
        bk.w = fminf(bk.w, k2.w);
    }
    const int idx[4] = {
        (int)(__float_as_uint(bk.x) & 1023u),
        (int)(__float_as_uint(bk.y) & 1023u),
        (int)(__float_as_uint(bk.z) & 1023u),
        (int)(__float_as_uint(bk.w) & 1023u)
    };

    // ---- preds + coalesced target block ----
    const float4* x4 = (const float4*)(X + (size_t)bt * (Nc * Dc));
    const float4 a0 = x4[3 * tid + 0];
    const float4 a1 = x4[3 * tid + 1];
    const float4 a2 = x4[3 * tid + 2];
    const float px[4] = {a0.x, a0.w, a1.z, a2.y};
    const float py[4] = {a0.y, a1.x, a1.w, a2.z};
    const float pz[4] = {a0.z, a1.y, a2.x, a2.w};

    const float4* t4 = (const float4*)(Tg + (size_t)bt * (Nc * Dc));
    const float4 r0 = t4[3 * tid + 0];
    const float4 r1 = t4[3 * tid + 1];
    const float4 r2 = t4[3 * tid + 2];

    // ---- gather winners, smooth-L1 ----
    const float* tb = Tg + (size_t)bt * (Nc * Dc);
    float s = 0.0f;
    #pragma unroll
    for (int k = 0; k < 4; ++k) {
        const float tx = tb[idx[k] * 3 + 0];
        const float ty = tb[idx[k] * 3 + 1];
        const float tz = tb[idx[k] * 3 + 2];
        s += sl1(px[k] - tx) + sl1(py[k] - ty) + sl1(pz[k] - tz);
    }

    // ---- 7 block reductions (loss + 3 pred sums + 3 target sums) ----
    float vals[7] = {
        s,
        px[0] + px[1] + px[2] + px[3],
        py[0] + py[1] + py[2] + py[3],
        pz[0] + pz[1] + pz[2] + pz[3],
        r0.x + r0.w + r1.z + r2.y,
        r0.y + r1.x + r1.w + r2.z,
        r0.z + r1.y + r2.x + r2.w
    };
    const int lane = tid & 63, wid = tid >> 6;
    #pragma unroll
    for (int k = 0; k < 7; ++k) {
        float v = vals[k];
        #pragma unroll
        for (int off = 32; off; off >>= 1) v += __shfl_down(v, off, 64);
        if (lane == 0) sred[wid][k] = v;
    }
    __syncthreads();
    if (tid == 0) {
        float tot[7];
        #pragma unroll
        for (int k = 0; k < 7; ++k)
            tot[k] = sred[0][k] + sred[1][k] + sred[2][k] + sred[3][k];
        // loss contribution: w_bt * (sl1 sum / (N*D)) / B
        atomicAdd(out, tot[0] * W[bt] * (1.0f / (Nc * Dc)) * (1.0f / Bc));
        // centroid contribution for this bt
        const float inv = 1.0f / Nc;
        float lc = sl1((tot[1] - tot[4]) * inv)
                 + sl1((tot[2] - tot[5]) * inv)
                 + sl1((tot[3] - tot[6]) * inv);
        atomicAdd(out + 1, lc * (1.0f / (Bc * Dc)));   // lossc = sum / (B*3)
    }
}

extern "C" void kernel_launch(void* const* d_in, const int* in_sizes, int n_in,
                              void* d_out, int out_size, void* d_ws, size_t ws_size,
                              hipStream_t stream) {
    const float* X  = (const float*)d_in[0];  // X_v        [4,28,1024,3]
    const float* Tg = (const float*)d_in[1];  // target_X_v [4,28,1024,3]
    const float* W  = (const float*)d_in[2];  // weights    [4,28]
    float* out = (float*)d_out;               // {loss, lossc}

    float4* bestkP = (float4*)d_ws;           // [NQ*BT*256] packed keys

    chamfer_kernel<<<BT * NQ, 256, 0, stream>>>(X, Tg, bestkP, out);
    gather_finalize_kernel<<<BT, 256, 0, stream>>>(X, Tg, W, bestkP, out);
}